// Round 8
// baseline (662.382 us; speedup 1.0000x reference)
//
#include <hip/hip_runtime.h>
#include <hip/hip_bf16.h>

#define NEDGE 800000
#define NNODE 100000
#define LATD  128
#define NHEAD 4
#define WPAD  136            // padded LDS row length (halves): 272B stride
#define TILES (NEDGE / 16)   // fallback only
#define QTILES (NNODE / 16)  // 6250 exact
#define NB ((NNODE + 1023) / 1024)  // 98 scan blocks
#define NWAVES 4096          // 512 blocks x 8 waves

typedef _Float16 half8 __attribute__((ext_vector_type(8)));
typedef float    f32x4 __attribute__((ext_vector_type(4)));

__device__ __forceinline__ int mn(int a, int b) { return a < b ? a : b; }

__device__ __forceinline__ half8 load_frag_f32(const float* __restrict__ p) {
    const f32x4 a = *reinterpret_cast<const f32x4*>(p);
    const f32x4 b = *reinterpret_cast<const f32x4*>(p + 4);
    half8 r;
    r[0] = (_Float16)a[0]; r[1] = (_Float16)a[1];
    r[2] = (_Float16)a[2]; r[3] = (_Float16)a[3];
    r[4] = (_Float16)b[0]; r[5] = (_Float16)b[1];
    r[6] = (_Float16)b[2]; r[7] = (_Float16)b[3];
    return r;
}

// ---------------- qAll = embeds @ Q, fp16, PERMUTED layout ----------------
// storage: qAll[n*128 + (col&15)*8 + (col>>4)]
__global__ __launch_bounds__(512, 2) void q_kernel(
    const float* __restrict__ embeds,
    const float* __restrict__ Qw,
    _Float16* __restrict__ qAll)
{
    extern __shared__ _Float16 lds[];
    _Float16* Qt = lds;  // Qt[c][d] = Q[d][c]
    const int t = threadIdx.x;
    for (int idx = t; idx < LATD * LATD; idx += 512) {
        const int d = idx >> 7, c = idx & 127;
        Qt[c * WPAD + d] = (_Float16)Qw[idx];
    }
    __syncthreads();

    const int lane = t & 63;
    const int c16  = lane & 15;
    const int g    = lane >> 4;
    const int wave = (blockIdx.x << 3) + (t >> 6);
    const int nw   = gridDim.x << 3;

    for (int tile = wave; tile < QTILES; tile += nw) {
        const int n0 = tile << 4;
        const float* xrow = embeds + (size_t)(n0 + c16) * LATD + g * 8;
        f32x4 accQ[8] = {};
        #pragma unroll
        for (int ks = 0; ks < 4; ++ks) {
            const half8 ax = load_frag_f32(xrow + ks * 32);
            const int ko = ks * 32 + g * 8;
            #pragma unroll
            for (int nt = 0; nt < 8; ++nt) {
                const half8 bq = *reinterpret_cast<const half8*>(Qt + (nt * 16 + c16) * WPAD + ko);
                accQ[nt] = __builtin_amdgcn_mfma_f32_16x16x32_f16(ax, bq, accQ[nt], 0, 0, 0);
            }
        }
        #pragma unroll
        for (int r = 0; r < 4; ++r) {
            half8 h;
            #pragma unroll
            for (int nt = 0; nt < 8; ++nt) h[nt] = (_Float16)accQ[nt][r];
            *reinterpret_cast<half8*>(qAll + (size_t)(n0 + g * 4 + r) * LATD + c16 * 8) = h;
        }
    }
}

// ---------------- CSR build ----------------
__global__ void hist_kernel(const int* __restrict__ rows, int* __restrict__ counts) {
    const int e = blockIdx.x * 256 + threadIdx.x;
    if (e < NEDGE) atomicAdd(&counts[rows[e]], 1);
}

__global__ __launch_bounds__(1024) void scan1_kernel(
    const int* __restrict__ counts, int* __restrict__ offsets, int* __restrict__ partials)
{
    __shared__ int wt[16];
    __shared__ int wp[16];
    const int b = blockIdx.x;
    const int i = b * 1024 + threadIdx.x;
    const int v = (i < NNODE) ? counts[i] : 0;
    const int lane = threadIdx.x & 63, wid = threadIdx.x >> 6;
    int incl = v;
    #pragma unroll
    for (int d = 1; d < 64; d <<= 1) {
        const int x = __shfl_up(incl, d);
        if (lane >= d) incl += x;
    }
    if (lane == 63) wt[wid] = incl;
    __syncthreads();
    if (threadIdx.x == 0) {
        int s = 0;
        for (int k = 0; k < 16; ++k) { wp[k] = s; s += wt[k]; }
        partials[b] = s;
    }
    __syncthreads();
    if (i < NNODE) offsets[i] = incl - v + wp[wid];
}

__global__ __launch_bounds__(1024) void scan2_kernel(
    int* __restrict__ offsets, int* __restrict__ cursor, const int* __restrict__ partials)
{
    __shared__ int sp[128];
    const int b = blockIdx.x;
    if (threadIdx.x < NB) sp[threadIdx.x] = partials[threadIdx.x];
    __syncthreads();
    int s = 0;
    for (int k = 0; k < b; ++k) s += sp[k];
    const int i = b * 1024 + threadIdx.x;
    if (i < NNODE) {
        const int val = offsets[i] + s;
        offsets[i] = val;
        cursor[i]  = val;
    }
    if (b == 0 && threadIdx.x == 0) offsets[NNODE] = NEDGE;
}

__global__ void scatter_kernel(const int* __restrict__ rows,
                               int* __restrict__ cursor,
                               int* __restrict__ edgeIdx,
                               int* __restrict__ rowsSorted) {
    const int e = blockIdx.x * 256 + threadIdx.x;
    if (e < NEDGE) {
        const int r = rows[e];
        const int p = atomicAdd(&cursor[r], 1);
        edgeIdx[p] = e;
        rowsSorted[p] = r;
    }
}

// -------- node-aligned wave partition: waveStart[w] = edge start of wave w --------
__global__ void partition_kernel(const int* __restrict__ offsets, int* __restrict__ waveStart) {
    const int w = blockIdx.x * 256 + threadIdx.x;
    if (w > NWAVES) return;
    if (w == NWAVES) { waveStart[w] = NEDGE; return; }
    const int tgt = (int)(((long long)w * NEDGE) / NWAVES);
    int lo = 0, hi = NNODE;             // smallest n with offsets[n] >= tgt
    while (lo < hi) {
        const int mid = (lo + hi) >> 1;
        if (offsets[mid] >= tgt) hi = mid; else lo = mid + 1;
    }
    waveStart[w] = offsets[lo];
}

// ------ chunk kernel: node-owned waves, P-MFMA segment totals, register carry,
//        plain coalesced stores (NO atomics), norm fused into the store ------
__global__ __launch_bounds__(512, 2) void chunk_kernel(
    const int*      __restrict__ waveStart,
    const int*      __restrict__ edgeIdx,
    const int*      __restrict__ rowsSorted,
    const float*    __restrict__ colEmb,
    const _Float16* __restrict__ qAll,
    const float*    __restrict__ Kw,
    const float*    __restrict__ Vw,
    float*          __restrict__ out)
{
    extern __shared__ _Float16 lds[];
    _Float16* Kt = lds;                 // Kt[c][d] = K[d][c]
    _Float16* Vt = lds + LATD * WPAD;
    const int t = threadIdx.x;
    for (int idx = t; idx < LATD * LATD; idx += 512) {
        const int d = idx >> 7, c = idx & 127;
        Kt[c * WPAD + d] = (_Float16)Kw[idx];
        Vt[c * WPAD + d] = (_Float16)Vw[idx];
    }
    __syncthreads();

    const int lane = t & 63;
    const int c16  = lane & 15;
    const int g    = lane >> 4;
    const int wave = blockIdx.x * 8 + (t >> 6);
    const int s = waveStart[wave];
    const int e = waveStart[wave + 1];

    float carryNum[8] = {0.f,0.f,0.f,0.f,0.f,0.f,0.f,0.f};
    float carryDen[4] = {0.f,0.f,0.f,0.f};
    int   carryNode = -1;

    for (int e0 = s; e0 < e; e0 += 16) {
        const int valid = e - e0;           // rows >= valid are padding
        const int last  = e - 1;
        const int b4 = e0 + g * 4;
        int4 rB;
        rB.x = rowsSorted[mn(b4 + 0, last)];
        rB.y = rowsSorted[mn(b4 + 1, last)];
        rB.z = rowsSorted[mn(b4 + 2, last)];
        rB.w = rowsSorted[mn(b4 + 3, last)];
        const int iA    = mn(e0 + c16, last);
        const int eA    = edgeIdx[iA];
        const int rid16 = rowsSorted[iA];

        const float* yrow = colEmb + (size_t)eA * LATD + g * 8;
        half8 ay[4];
        #pragma unroll
        for (int ks = 0; ks < 4; ++ks) ay[ks] = load_frag_f32(yrow + ks * 32);

        half8 qv[4];
        qv[0] = *reinterpret_cast<const half8*>(qAll + (size_t)rB.x * LATD + c16 * 8);
        qv[1] = *reinterpret_cast<const half8*>(qAll + (size_t)rB.y * LATD + c16 * 8);
        qv[2] = *reinterpret_cast<const half8*>(qAll + (size_t)rB.z * LATD + c16 * 8);
        qv[3] = *reinterpret_cast<const half8*>(qAll + (size_t)rB.w * LATD + c16 * 8);

        f32x4 accK[8] = {};
        #pragma unroll
        for (int ks = 0; ks < 4; ++ks) {
            const int ko = ks * 32 + g * 8;
            #pragma unroll
            for (int nt = 0; nt < 8; ++nt) {
                const half8 bk = *reinterpret_cast<const half8*>(Kt + (nt * 16 + c16) * WPAD + ko);
                accK[nt] = __builtin_amdgcn_mfma_f32_16x16x32_f16(ay[ks], bk, accK[nt], 0, 0, 0);
            }
        }

        // softmax numerators: eh[h][r] = exp(clip(q.k)), padded rows zeroed
        f32x4 eh[4];
        #pragma unroll
        for (int h = 0; h < 4; ++h) {
            f32x4 p;
            #pragma unroll
            for (int r = 0; r < 4; ++r)
                p[r] = accK[2 * h][r]     * (float)qv[r][2 * h]
                     + accK[2 * h + 1][r] * (float)qv[r][2 * h + 1];
            #pragma unroll
            for (int m = 1; m < 16; m <<= 1) {
                f32x4 q;
                q[0] = __shfl_xor(p[0], m);
                q[1] = __shfl_xor(p[1], m);
                q[2] = __shfl_xor(p[2], m);
                q[3] = __shfl_xor(p[3], m);
                p += q;
            }
            #pragma unroll
            for (int r = 0; r < 4; ++r)
                eh[h][r] = expf(fminf(10.0f, fmaxf(-10.0f, p[r])));
        }
        #pragma unroll
        for (int r = 0; r < 4; ++r) {
            if (4 * g + r >= valid) {
                eh[0][r] = 0.f; eh[1][r] = 0.f; eh[2][r] = 0.f; eh[3][r] = 0.f;
            }
        }

        // v matmul
        f32x4 accV[8] = {};
        #pragma unroll
        for (int ks = 0; ks < 4; ++ks) {
            const int ko = ks * 32 + g * 8;
            #pragma unroll
            for (int nt = 0; nt < 8; ++nt) {
                const half8 bv = *reinterpret_cast<const half8*>(Vt + (nt * 16 + c16) * WPAD + ko);
                accV[nt] = __builtin_amdgcn_mfma_f32_16x16x32_f16(ay[ks], bv, accV[nt], 0, 0, 0);
            }
        }

        // ---- P-MFMA segment totals (R7 machinery) ----
        half8 Pf = {};
        Pf[0] = (rB.x == rid16) ? (_Float16)1.f : (_Float16)0.f;
        Pf[1] = (rB.y == rid16) ? (_Float16)1.f : (_Float16)0.f;
        Pf[2] = (rB.z == rid16) ? (_Float16)1.f : (_Float16)0.f;
        Pf[3] = (rB.w == rid16) ? (_Float16)1.f : (_Float16)0.f;

        const f32x4 zero4 = {};
        f32x4 D[8];
        #pragma unroll
        for (int nt = 0; nt < 8; ++nt) {
            const f32x4 w4 = accV[nt] * eh[nt >> 1] * 0.015625f;   // 2^-6 fp16 guard
            half8 Wf = {};
            Wf[0] = (_Float16)w4[0]; Wf[1] = (_Float16)w4[1];
            Wf[2] = (_Float16)w4[2]; Wf[3] = (_Float16)w4[3];
            D[nt] = __builtin_amdgcn_mfma_f32_16x16x32_f16(Pf, Wf, zero4, 0, 0, 0);
        }
        const f32x4 sel = (c16 == 0) ? eh[0] : (c16 == 1) ? eh[1] : (c16 == 2) ? eh[2] : eh[3];
        half8 Df = {};
        if (c16 < NHEAD) {
            Df[0] = (_Float16)sel[0]; Df[1] = (_Float16)sel[1];
            Df[2] = (_Float16)sel[2]; Df[3] = (_Float16)sel[3];
        }
        const f32x4 Dden = __builtin_amdgcn_mfma_f32_16x16x32_f16(Pf, Df, zero4, 0, 0, 0);

        // ---- head mask over the 16 sorted rows (prev of row0 = carryNode) ----
        int prevNode = __shfl_up(rB.w, 16);
        if (g == 0) prevNode = carryNode;
        const bool h0 = (rB.x != prevNode);
        const bool h1 = (rB.y != rB.x);
        const bool h2 = (rB.z != rB.y);
        const bool h3 = (rB.w != rB.z);
        const unsigned long long m0 = __ballot(h0);
        const unsigned long long m1 = __ballot(h1);
        const unsigned long long m2 = __ballot(h2);
        const unsigned long long m3 = __ballot(h3);
        unsigned hm = 0;
        #pragma unroll
        for (int gg = 0; gg < 4; ++gg) {
            hm |= (unsigned)((m0 >> (gg * 16)) & 1ULL) << (4 * gg + 0);
            hm |= (unsigned)((m1 >> (gg * 16)) & 1ULL) << (4 * gg + 1);
            hm |= (unsigned)((m2 >> (gg * 16)) & 1ULL) << (4 * gg + 2);
            hm |= (unsigned)((m3 >> (gg * 16)) & 1ULL) << (4 * gg + 3);
        }

        // broadcast row0 segment totals (held by g=0 lanes)
        float Df8[8];
        #pragma unroll
        for (int nt = 0; nt < 8; ++nt) Df8[nt] = __shfl(D[nt][0], c16);
        float Dd4[4];
        #pragma unroll
        for (int h = 0; h < 4; ++h) Dd4[h] = __shfl(Dden[0], h);

        if (!(hm & 1)) {   // row0 continues the carry node
            #pragma unroll
            for (int nt = 0; nt < 8; ++nt) carryNum[nt] += Df8[nt];
            #pragma unroll
            for (int h = 0; h < 4; ++h) carryDen[h] += Dd4[h];
        }

        if (hm != 0) {
            // carry closes -> final value, plain store (norm fused)
            if (carryNode >= 0) {
                #pragma unroll
                for (int nt = 0; nt < 8; ++nt)
                    out[(size_t)carryNode * LATD + nt * 16 + c16] =
                        carryNum[nt] * 64.0f / (carryDen[nt >> 1] + 1e-8f);
            }
            // in-tile closed segments
            #pragma unroll
            for (int r = 0; r < 4; ++r) {
                const int i = 4 * g + r;
                float den_h[4];
                #pragma unroll
                for (int h = 0; h < 4; ++h) den_h[h] = __shfl(Dden[r], g * 16 + h);
                const int nodeR = (r == 0) ? rB.x : (r == 1) ? rB.y : (r == 2) ? rB.z : rB.w;
                const bool doFlush = ((hm >> i) & 1) && ((hm >> (i + 1)) != 0);
                if (doFlush) {
                    #pragma unroll
                    for (int nt = 0; nt < 8; ++nt)
                        out[(size_t)nodeR * LATD + nt * 16 + c16] =
                            D[nt][r] * 64.0f / (den_h[nt >> 1] + 1e-8f);
                }
            }
            // new carry = last head's segment
            const int il = 31 - __clz(hm);
            const int sg = il >> 2, sr = il & 3;
            const int nodeSel = (sr == 0) ? rB.x : (sr == 1) ? rB.y : (sr == 2) ? rB.z : rB.w;
            carryNode = __shfl(nodeSel, sg * 16);
            #pragma unroll
            for (int nt = 0; nt < 8; ++nt) {
                const float dsel = (sr == 0) ? D[nt][0] : (sr == 1) ? D[nt][1]
                                 : (sr == 2) ? D[nt][2] : D[nt][3];
                carryNum[nt] = __shfl(dsel, sg * 16 + c16);
            }
            const float ddsel = (sr == 0) ? Dden[0] : (sr == 1) ? Dden[1]
                              : (sr == 2) ? Dden[2] : Dden[3];
            #pragma unroll
            for (int h = 0; h < 4; ++h) carryDen[h] = __shfl(ddsel, sg * 16 + h);
        }
    }

    // final flush
    if (carryNode >= 0) {
        #pragma unroll
        for (int nt = 0; nt < 8; ++nt)
            out[(size_t)carryNode * LATD + nt * 16 + c16] =
                carryNum[nt] * 64.0f / (carryDen[nt >> 1] + 1e-8f);
    }
}

// out[n, j] /= (attNorm[n, j/32] + 1e-8)   (fallback path only)
__global__ void norm_kernel(float* __restrict__ out, const float* __restrict__ attNorm) {
    const int i = blockIdx.x * 256 + threadIdx.x;
    if (i >= NNODE * 32) return;
    const int n = i >> 5;
    const int h = (i & 31) >> 3;
    const float s = attNorm[n * NHEAD + h] + 1e-8f;
    f32x4* p = reinterpret_cast<f32x4*>(out) + i;
    f32x4 v = *p;
    v[0] /= s; v[1] /= s; v[2] /= s; v[3] /= s;
    *p = v;
}

// ================= fallback (round-1 scatter path, unsorted) =================
__global__ __launch_bounds__(512, 2) void edge_kernel(
    const int*   __restrict__ rows,
    const float* __restrict__ colEmb,
    const float* __restrict__ embeds,
    const float* __restrict__ Qw,
    const float* __restrict__ Kw,
    const float* __restrict__ Vw,
    float* __restrict__ outAcc,
    float* __restrict__ attNorm)
{
    extern __shared__ _Float16 lds[];
    _Float16* Qt = lds;
    _Float16* Kt = lds + LATD * WPAD;
    _Float16* Vt = lds + 2 * LATD * WPAD;
    const int t = threadIdx.x;
    for (int idx = t; idx < LATD * LATD; idx += 512) {
        const int d = idx >> 7, c = idx & 127;
        Qt[c * WPAD + d] = (_Float16)Qw[idx];
        Kt[c * WPAD + d] = (_Float16)Kw[idx];
        Vt[c * WPAD + d] = (_Float16)Vw[idx];
    }
    __syncthreads();
    const int lane = t & 63;
    const int c16  = lane & 15;
    const int g    = lane >> 4;
    const int wave = (blockIdx.x << 3) + (t >> 6);
    const int nw   = gridDim.x << 3;
    for (int tile = wave; tile < TILES; tile += nw) {
        const int e0 = tile << 4;
        const int eA = e0 + c16;
        const int rA = rows[eA];
        const float* xrow = embeds + (size_t)rA * LATD + g * 8;
        const float* yrow = colEmb + (size_t)eA * LATD + g * 8;
        half8 ay[4];
        f32x4 accQ[8] = {};
        f32x4 accK[8] = {};
        #pragma unroll
        for (int ks = 0; ks < 4; ++ks) {
            const int ko = ks * 32 + g * 8;
            const half8 ax = load_frag_f32(xrow + ks * 32);
            ay[ks] = load_frag_f32(yrow + ks * 32);
            #pragma unroll
            for (int nt = 0; nt < 8; ++nt) {
                const int rofs = (nt * 16 + c16) * WPAD + ko;
                const half8 bq = *reinterpret_cast<const half8*>(Qt + rofs);
                const half8 bk = *reinterpret_cast<const half8*>(Kt + rofs);
                accQ[nt] = __builtin_amdgcn_mfma_f32_16x16x32_f16(ax,     bq, accQ[nt], 0, 0, 0);
                accK[nt] = __builtin_amdgcn_mfma_f32_16x16x32_f16(ay[ks], bk, accK[nt], 0, 0, 0);
            }
        }
        f32x4 eh[4];
        #pragma unroll
        for (int h = 0; h < 4; ++h) {
            f32x4 p = accQ[2 * h] * accK[2 * h] + accQ[2 * h + 1] * accK[2 * h + 1];
            #pragma unroll
            for (int m = 1; m < 16; m <<= 1) {
                f32x4 q;
                q[0] = __shfl_xor(p[0], m);
                q[1] = __shfl_xor(p[1], m);
                q[2] = __shfl_xor(p[2], m);
                q[3] = __shfl_xor(p[3], m);
                p += q;
            }
            #pragma unroll
            for (int r = 0; r < 4; ++r)
                eh[h][r] = expf(fminf(10.0f, fmaxf(-10.0f, p[r])));
        }
        int rB[4];
        #pragma unroll
        for (int r = 0; r < 4; ++r) rB[r] = rows[e0 + g * 4 + r];
        if (c16 < NHEAD) {
            const f32x4 sel = (c16 == 0) ? eh[0] : (c16 == 1) ? eh[1] : (c16 == 2) ? eh[2] : eh[3];
            #pragma unroll
            for (int r = 0; r < 4; ++r)
                atomicAdd(attNorm + rB[r] * NHEAD + c16, sel[r]);
        }
        f32x4 accV[8] = {};
        #pragma unroll
        for (int ks = 0; ks < 4; ++ks) {
            const int ko = ks * 32 + g * 8;
            #pragma unroll
            for (int nt = 0; nt < 8; ++nt) {
                const half8 bv = *reinterpret_cast<const half8*>(Vt + (nt * 16 + c16) * WPAD + ko);
                accV[nt] = __builtin_amdgcn_mfma_f32_16x16x32_f16(ay[ks], bv, accV[nt], 0, 0, 0);
            }
        }
        #pragma unroll
        for (int nt = 0; nt < 8; ++nt) {
            const f32x4 w = accV[nt] * eh[nt >> 1];
            #pragma unroll
            for (int r = 0; r < 4; ++r)
                atomicAdd(outAcc + (size_t)rB[r] * LATD + nt * 16 + c16, w[r]);
        }
    }
}

extern "C" void kernel_launch(void* const* d_in, const int* in_sizes, int n_in,
                              void* d_out, int out_size, void* d_ws, size_t ws_size,
                              hipStream_t stream) {
    const int*   rows   = (const int*)d_in[0];
    const float* colEmb = (const float*)d_in[1];
    const float* embeds = (const float*)d_in[2];
    const float* Qw     = (const float*)d_in[3];
    const float* Kw     = (const float*)d_in[4];
    const float* Vw     = (const float*)d_in[5];
    float* out = (float*)d_out;

    // ws layout
    const size_t qAllB  = (size_t)NNODE * LATD * sizeof(_Float16); // 25.6 MB
    const size_t cntB   = 400128;                         // NNODE ints, padded
    const size_t offB   = 402048;                         // (NNODE+1) ints, padded
    const size_t curB   = 400128;
    const size_t eidxB  = (size_t)NEDGE * sizeof(int);    // 3.2 MB
    const size_t rsrtB  = (size_t)NEDGE * sizeof(int);    // 3.2 MB
    const size_t partB  = 512;
    const size_t wstB   = (size_t)(NWAVES + 1) * sizeof(int) + 256;
    const size_t needed = qAllB + cntB + offB + curB + eidxB + rsrtB + partB + wstB;

    if (ws_size >= needed) {
        char* w = (char*)d_ws;
        _Float16* qAll    = (_Float16*)w; w += qAllB;
        int*   counts     = (int*)w;    w += cntB;
        int*   offsets    = (int*)w;    w += offB;
        int*   cursor     = (int*)w;    w += curB;
        int*   edgeIdx    = (int*)w;    w += eidxB;
        int*   rowsSorted = (int*)w;    w += rsrtB;
        int*   partials   = (int*)w;    w += partB;
        int*   waveStart  = (int*)w;

        hipMemsetAsync(counts, 0, (size_t)NNODE * sizeof(int), stream);
        hipMemsetAsync(out,    0, (size_t)NNODE * LATD * sizeof(float), stream); // deg-0 nodes

        const int ldsQ = LATD * WPAD * sizeof(_Float16);      // 34,816 B
        hipFuncSetAttribute((const void*)q_kernel,
                            hipFuncAttributeMaxDynamicSharedMemorySize, ldsQ);
        q_kernel<<<(QTILES + 7) / 8, 512, ldsQ, stream>>>(embeds, Qw, qAll);

        hist_kernel<<<(NEDGE + 255) / 256, 256, 0, stream>>>(rows, counts);
        scan1_kernel<<<NB, 1024, 0, stream>>>(counts, offsets, partials);
        scan2_kernel<<<NB, 1024, 0, stream>>>(offsets, cursor, partials);
        scatter_kernel<<<(NEDGE + 255) / 256, 256, 0, stream>>>(rows, cursor, edgeIdx, rowsSorted);
        partition_kernel<<<(NWAVES + 256) / 256, 256, 0, stream>>>(offsets, waveStart);

        const int ldsN = 2 * LATD * WPAD * sizeof(_Float16);  // 69,632 B
        hipFuncSetAttribute((const void*)chunk_kernel,
                            hipFuncAttributeMaxDynamicSharedMemorySize, ldsN);
        chunk_kernel<<<512, 512, ldsN, stream>>>(
            waveStart, edgeIdx, rowsSorted, colEmb, qAll, Kw, Vw, out);
    } else {
        // fallback: round-1 scatter path
        float* attNorm = (float*)d_ws;
        const int ldsBytes = 3 * LATD * WPAD * sizeof(_Float16);  // 104448 B
        hipMemsetAsync(out,     0, (size_t)NNODE * LATD  * sizeof(float), stream);
        hipMemsetAsync(attNorm, 0, (size_t)NNODE * NHEAD * sizeof(float), stream);
        hipFuncSetAttribute((const void*)edge_kernel,
                            hipFuncAttributeMaxDynamicSharedMemorySize, ldsBytes);
        edge_kernel<<<512, 512, ldsBytes, stream>>>(rows, colEmb, embeds, Qw, Kw, Vw, out, attNorm);
        const int nVec = NNODE * 32;
        norm_kernel<<<(nVec + 255) / 256, 256, 0, stream>>>(out, attNorm);
    }
}

// Round 9
// 624.839 us; speedup vs baseline: 1.0601x; 1.0601x over previous
//
#include <hip/hip_runtime.h>
#include <hip/hip_bf16.h>

#define NEDGE 800000
#define NNODE 100000
#define LATD  128
#define NHEAD 4
#define WPAD  136            // padded LDS row length (halves): 272B stride
#define TILES (NEDGE / 16)   // 50000 exact
#define QTILES (NNODE / 16)  // 6250 exact
#define NB ((NNODE + 1023) / 1024)  // 98 scan blocks
#define NW2 8192             // accum waves

typedef _Float16 half8 __attribute__((ext_vector_type(8)));
typedef _Float16 half2t __attribute__((ext_vector_type(2)));
typedef float    f32x4 __attribute__((ext_vector_type(4)));

__device__ __forceinline__ int mn(int a, int b) { return a < b ? a : b; }

__device__ __forceinline__ half8 load_frag_f32(const float* __restrict__ p) {
    const f32x4 a = *reinterpret_cast<const f32x4*>(p);
    const f32x4 b = *reinterpret_cast<const f32x4*>(p + 4);
    half8 r;
    r[0] = (_Float16)a[0]; r[1] = (_Float16)a[1];
    r[2] = (_Float16)a[2]; r[3] = (_Float16)a[3];
    r[4] = (_Float16)b[0]; r[5] = (_Float16)b[1];
    r[6] = (_Float16)b[2]; r[7] = (_Float16)b[3];
    return r;
}

// ---------------- qAll = embeds @ Q, fp16, PERMUTED layout ----------------
// storage: qAll[n*128 + (col&15)*8 + (col>>4)]
__global__ __launch_bounds__(512, 2) void q_kernel(
    const float* __restrict__ embeds,
    const float* __restrict__ Qw,
    _Float16* __restrict__ qAll)
{
    extern __shared__ _Float16 lds[];
    _Float16* Qt = lds;  // Qt[c][d] = Q[d][c]
    const int t = threadIdx.x;
    for (int idx = t; idx < LATD * LATD; idx += 512) {
        const int d = idx >> 7, c = idx & 127;
        Qt[c * WPAD + d] = (_Float16)Qw[idx];
    }
    __syncthreads();

    const int lane = t & 63;
    const int c16  = lane & 15;
    const int g    = lane >> 4;
    const int wave = (blockIdx.x << 3) + (t >> 6);
    const int nw   = gridDim.x << 3;

    for (int tile = wave; tile < QTILES; tile += nw) {
        const int n0 = tile << 4;
        const float* xrow = embeds + (size_t)(n0 + c16) * LATD + g * 8;
        f32x4 accQ[8] = {};
        #pragma unroll
        for (int ks = 0; ks < 4; ++ks) {
            const half8 ax = load_frag_f32(xrow + ks * 32);
            const int ko = ks * 32 + g * 8;
            #pragma unroll
            for (int nt = 0; nt < 8; ++nt) {
                const half8 bq = *reinterpret_cast<const half8*>(Qt + (nt * 16 + c16) * WPAD + ko);
                accQ[nt] = __builtin_amdgcn_mfma_f32_16x16x32_f16(ax, bq, accQ[nt], 0, 0, 0);
            }
        }
        #pragma unroll
        for (int r = 0; r < 4; ++r) {
            half8 h;
            #pragma unroll
            for (int nt = 0; nt < 8; ++nt) h[nt] = (_Float16)accQ[nt][r];
            *reinterpret_cast<half8*>(qAll + (size_t)(n0 + g * 4 + r) * LATD + c16 * 8) = h;
        }
    }
}

// ---------------- CSR build ----------------
__global__ void hist_kernel(const int* __restrict__ rows, int* __restrict__ counts) {
    const int e = blockIdx.x * 256 + threadIdx.x;
    if (e < NEDGE) atomicAdd(&counts[rows[e]], 1);
}

__global__ __launch_bounds__(1024) void scan1_kernel(
    const int* __restrict__ counts, int* __restrict__ offsets, int* __restrict__ partials)
{
    __shared__ int wt[16];
    __shared__ int wp[16];
    const int b = blockIdx.x;
    const int i = b * 1024 + threadIdx.x;
    const int v = (i < NNODE) ? counts[i] : 0;
    const int lane = threadIdx.x & 63, wid = threadIdx.x >> 6;
    int incl = v;
    #pragma unroll
    for (int d = 1; d < 64; d <<= 1) {
        const int x = __shfl_up(incl, d);
        if (lane >= d) incl += x;
    }
    if (lane == 63) wt[wid] = incl;
    __syncthreads();
    if (threadIdx.x == 0) {
        int s = 0;
        for (int k = 0; k < 16; ++k) { wp[k] = s; s += wt[k]; }
        partials[b] = s;
    }
    __syncthreads();
    if (i < NNODE) offsets[i] = incl - v + wp[wid];
}

__global__ __launch_bounds__(1024) void scan2_kernel(
    int* __restrict__ offsets, int* __restrict__ cursor, const int* __restrict__ partials)
{
    __shared__ int sp[128];
    const int b = blockIdx.x;
    if (threadIdx.x < NB) sp[threadIdx.x] = partials[threadIdx.x];
    __syncthreads();
    int s = 0;
    for (int k = 0; k < b; ++k) s += sp[k];
    const int i = b * 1024 + threadIdx.x;
    if (i < NNODE) {
        const int val = offsets[i] + s;
        offsets[i] = val;
        cursor[i]  = val;
    }
    if (b == 0 && threadIdx.x == 0) offsets[NNODE] = NEDGE;
}

__global__ void scatter_kernel(const int* __restrict__ rows,
                               int* __restrict__ cursor,
                               int* __restrict__ edgeIdx,
                               int* __restrict__ rowsSorted,
                               int* __restrict__ rank) {
    const int e = blockIdx.x * 256 + threadIdx.x;
    if (e < NEDGE) {
        const int r = rows[e];
        const int p = atomicAdd(&cursor[r], 1);
        edgeIdx[p]    = e;
        rowsSorted[p] = r;
        rank[e]       = p;
    }
}

// -------- node-aligned wave partition: waveStart[w] = edge start of wave w --------
__global__ void partition_kernel(const int* __restrict__ offsets, int* __restrict__ waveStart) {
    const int w = blockIdx.x * 256 + threadIdx.x;
    if (w > NW2) return;
    if (w == NW2) { waveStart[w] = NEDGE; return; }
    const int tgt = (int)(((long long)w * NEDGE) / NW2);
    int lo = 0, hi = NNODE;             // smallest n with offsets[n] >= tgt
    while (lo < hi) {
        const int mid = (lo + hi) >> 1;
        if (offsets[mid] >= tgt) hi = mid; else lo = mid + 1;
    }
    waveStart[w] = offsets[lo];
}

// ------ phase 1: k/v transform, natural-order streaming reads, sorted-slot writes ------
// kS/vS permuted per row: kS[p*128 + (col&15)*8 + (col>>4)]
__global__ __launch_bounds__(512, 2) void kv_kernel(
    const int*   __restrict__ rank,
    const float* __restrict__ colEmb,
    const float* __restrict__ Kw,
    const float* __restrict__ Vw,
    _Float16* __restrict__ kS,
    _Float16* __restrict__ vS)
{
    extern __shared__ _Float16 lds[];
    _Float16* Kt = lds;                 // Kt[c][d] = K[d][c]
    _Float16* Vt = lds + LATD * WPAD;
    const int t = threadIdx.x;
    for (int idx = t; idx < LATD * LATD; idx += 512) {
        const int d = idx >> 7, c = idx & 127;
        Kt[c * WPAD + d] = (_Float16)Kw[idx];
        Vt[c * WPAD + d] = (_Float16)Vw[idx];
    }
    __syncthreads();

    const int lane = t & 63;
    const int c16  = lane & 15;
    const int g    = lane >> 4;
    const int wave = blockIdx.x * 8 + (t >> 6);
    const int nw   = gridDim.x * 8;

    for (int tile = wave; tile < TILES; tile += nw) {
        const int e0 = tile << 4;
        const float* yrow = colEmb + (size_t)(e0 + c16) * LATD + g * 8;

        half8 ay[4];
        #pragma unroll
        for (int ks = 0; ks < 4; ++ks) ay[ks] = load_frag_f32(yrow + ks * 32);

        const int4 rk = *reinterpret_cast<const int4*>(rank + e0 + g * 4);

        f32x4 accK[8] = {};
        f32x4 accV[8] = {};
        #pragma unroll
        for (int ks = 0; ks < 4; ++ks) {
            const int ko = ks * 32 + g * 8;
            #pragma unroll
            for (int nt = 0; nt < 8; ++nt) {
                const half8 bk = *reinterpret_cast<const half8*>(Kt + (nt * 16 + c16) * WPAD + ko);
                const half8 bv = *reinterpret_cast<const half8*>(Vt + (nt * 16 + c16) * WPAD + ko);
                accK[nt] = __builtin_amdgcn_mfma_f32_16x16x32_f16(ay[ks], bk, accK[nt], 0, 0, 0);
                accV[nt] = __builtin_amdgcn_mfma_f32_16x16x32_f16(ay[ks], bv, accV[nt], 0, 0, 0);
            }
        }

        // D layout: row = g*4 + r (edge e0+4g+r), col = nt*16 + c16.
        // permuted store: block index = c16, item = nt  -> one half8 per row per matrix.
        #pragma unroll
        for (int r = 0; r < 4; ++r) {
            const int p = (r == 0) ? rk.x : (r == 1) ? rk.y : (r == 2) ? rk.z : rk.w;
            half8 hk, hv;
            #pragma unroll
            for (int nt = 0; nt < 8; ++nt) {
                hk[nt] = (_Float16)accK[nt][r];
                hv[nt] = (_Float16)accV[nt][r];
            }
            *reinterpret_cast<half8*>(kS + (size_t)p * LATD + c16 * 8) = hk;
            *reinterpret_cast<half8*>(vS + (size_t)p * LATD + c16 * 8) = hv;
        }
    }
}

// ------ phase 2: scalar accumulation, sequential kS/vS stream, no atomics ------
// lane's two cols: c0 = (lane>>2) + 32*(lane&3), c1 = c0+16; head = lane&3.
__global__ __launch_bounds__(256, 8) void accum_kernel(
    const int*      __restrict__ waveStart,
    const int*      __restrict__ rowsSorted,
    const _Float16* __restrict__ kS,
    const _Float16* __restrict__ vS,
    const _Float16* __restrict__ qAll,
    float*          __restrict__ out)
{
    const int lane = threadIdx.x & 63;
    const int wave = blockIdx.x * 4 + (threadIdx.x >> 6);
    int p = waveStart[wave];
    const int e = waveStart[wave + 1];
    if (p >= e) return;

    const int c0 = (lane >> 2) + 32 * (lane & 3);
    const int c1 = c0 + 16;
    const size_t lofs = (size_t)lane * 2;   // half index within a permuted 128-half row

    int curNode = rowsSorted[p];
    half2t qp = *reinterpret_cast<const half2t*>(qAll + (size_t)curNode * LATD + lofs);
    float q0 = (float)qp[0], q1 = (float)qp[1];

    float num0 = 0.f, num1 = 0.f, den = 0.f;

    for (; p < e; ++p) {
        const int rn = (p + 1 < e) ? rowsSorted[p + 1] : -1;  // prefetch next node id
        const half2t kp = *reinterpret_cast<const half2t*>(kS + (size_t)p * LATD + lofs);
        const half2t vp = *reinterpret_cast<const half2t*>(vS + (size_t)p * LATD + lofs);

        float s = q0 * (float)kp[0] + q1 * (float)kp[1];
        s += __shfl_xor(s, 4);
        s += __shfl_xor(s, 8);
        s += __shfl_xor(s, 16);
        s += __shfl_xor(s, 32);
        const float att = expf(fminf(10.0f, fmaxf(-10.0f, s)));

        num0 += att * (float)vp[0];
        num1 += att * (float)vp[1];
        den  += att;

        if (rn >= 0 && rn != curNode) {
            const float inv = 1.0f / (den + 1e-8f);
            out[(size_t)curNode * LATD + c0] = num0 * inv;
            out[(size_t)curNode * LATD + c1] = num1 * inv;
            num0 = 0.f; num1 = 0.f; den = 0.f;
            curNode = rn;
            qp = *reinterpret_cast<const half2t*>(qAll + (size_t)curNode * LATD + lofs);
            q0 = (float)qp[0]; q1 = (float)qp[1];
        }
    }
    const float inv = 1.0f / (den + 1e-8f);
    out[(size_t)curNode * LATD + c0] = num0 * inv;
    out[(size_t)curNode * LATD + c1] = num1 * inv;
}

// ====== mid-tier (R7): sorted-edge fused kernel with P-MFMA segment totals ======
__global__ __launch_bounds__(512, 2) void sorted_edge_kernel(
    const int*      __restrict__ edgeIdx,
    const int*      __restrict__ rowsSorted,
    const float*    __restrict__ colEmb,
    const _Float16* __restrict__ qAll,
    const float*    __restrict__ Kw,
    const float*    __restrict__ Vw,
    float* __restrict__ outAcc,
    float* __restrict__ attNorm,
    int tilesPerWave)
{
    extern __shared__ _Float16 lds[];
    _Float16* Kt = lds;
    _Float16* Vt = lds + LATD * WPAD;
    const int t = threadIdx.x;
    for (int idx = t; idx < LATD * LATD; idx += 512) {
        const int d = idx >> 7, c = idx & 127;
        Kt[c * WPAD + d] = (_Float16)Kw[idx];
        Vt[c * WPAD + d] = (_Float16)Vw[idx];
    }
    __syncthreads();

    const int lane = t & 63;
    const int c16  = lane & 15;
    const int g    = lane >> 4;
    const int wave = blockIdx.x * 8 + (t >> 6);
    const int tile0 = wave * tilesPerWave;
    int tile1 = tile0 + tilesPerWave;
    if (tile1 > TILES) tile1 = TILES;

    for (int tile = tile0; tile < tile1; ++tile) {
        const int e0 = tile << 4;
        const int eA    = edgeIdx[e0 + c16];
        const int rid16 = rowsSorted[e0 + c16];
        const int4 rB = *reinterpret_cast<const int4*>(rowsSorted + e0 + g * 4);
        const int prevRow = (g == 0) ? -1 : rowsSorted[e0 + 4 * g - 1];
        const float* yrow = colEmb + (size_t)eA * LATD + g * 8;

        half8 ay[4];
        #pragma unroll
        for (int ks = 0; ks < 4; ++ks) ay[ks] = load_frag_f32(yrow + ks * 32);

        half8 qv[4];
        qv[0] = *reinterpret_cast<const half8*>(qAll + (size_t)rB.x * LATD + c16 * 8);
        qv[1] = *reinterpret_cast<const half8*>(qAll + (size_t)rB.y * LATD + c16 * 8);
        qv[2] = *reinterpret_cast<const half8*>(qAll + (size_t)rB.z * LATD + c16 * 8);
        qv[3] = *reinterpret_cast<const half8*>(qAll + (size_t)rB.w * LATD + c16 * 8);

        f32x4 accK[8] = {};
        #pragma unroll
        for (int ks = 0; ks < 4; ++ks) {
            const int ko = ks * 32 + g * 8;
            #pragma unroll
            for (int nt = 0; nt < 8; ++nt) {
                const half8 bk = *reinterpret_cast<const half8*>(Kt + (nt * 16 + c16) * WPAD + ko);
                accK[nt] = __builtin_amdgcn_mfma_f32_16x16x32_f16(ay[ks], bk, accK[nt], 0, 0, 0);
            }
        }

        f32x4 eh[4];
        #pragma unroll
        for (int h = 0; h < 4; ++h) {
            f32x4 p;
            #pragma unroll
            for (int r = 0; r < 4; ++r)
                p[r] = accK[2 * h][r]     * (float)qv[r][2 * h]
                     + accK[2 * h + 1][r] * (float)qv[r][2 * h + 1];
            #pragma unroll
            for (int m = 1; m < 16; m <<= 1) {
                f32x4 q;
                q[0] = __shfl_xor(p[0], m);
                q[1] = __shfl_xor(p[1], m);
                q[2] = __shfl_xor(p[2], m);
                q[3] = __shfl_xor(p[3], m);
                p += q;
            }
            #pragma unroll
            for (int r = 0; r < 4; ++r)
                eh[h][r] = expf(fminf(10.0f, fmaxf(-10.0f, p[r])));
        }

        f32x4 accV[8] = {};
        #pragma unroll
        for (int ks = 0; ks < 4; ++ks) {
            const int ko = ks * 32 + g * 8;
            #pragma unroll
            for (int nt = 0; nt < 8; ++nt) {
                const half8 bv = *reinterpret_cast<const half8*>(Vt + (nt * 16 + c16) * WPAD + ko);
                accV[nt] = __builtin_amdgcn_mfma_f32_16x16x32_f16(ay[ks], bv, accV[nt], 0, 0, 0);
            }
        }

        half8 Pf = {};
        Pf[0] = (rB.x == rid16) ? (_Float16)1.f : (_Float16)0.f;
        Pf[1] = (rB.y == rid16) ? (_Float16)1.f : (_Float16)0.f;
        Pf[2] = (rB.z == rid16) ? (_Float16)1.f : (_Float16)0.f;
        Pf[3] = (rB.w == rid16) ? (_Float16)1.f : (_Float16)0.f;

        const f32x4 zero4 = {};
        f32x4 D[8];
        #pragma unroll
        for (int nt = 0; nt < 8; ++nt) {
            const f32x4 w4 = accV[nt] * eh[nt >> 1] * 0.015625f;
            half8 Wf = {};
            Wf[0] = (_Float16)w4[0]; Wf[1] = (_Float16)w4[1];
            Wf[2] = (_Float16)w4[2]; Wf[3] = (_Float16)w4[3];
            D[nt] = __builtin_amdgcn_mfma_f32_16x16x32_f16(Pf, Wf, zero4, 0, 0, 0);
        }
        const f32x4 sel = (c16 == 0) ? eh[0] : (c16 == 1) ? eh[1] : (c16 == 2) ? eh[2] : eh[3];
        half8 Df = {};
        if (c16 < NHEAD) {
            Df[0] = (_Float16)sel[0]; Df[1] = (_Float16)sel[1];
            Df[2] = (_Float16)sel[2]; Df[3] = (_Float16)sel[3];
        }
        const f32x4 Dden = __builtin_amdgcn_mfma_f32_16x16x32_f16(Pf, Df, zero4, 0, 0, 0);

        #pragma unroll
        for (int r = 0; r < 4; ++r) {
            const int cur = (r == 0) ? rB.x : (r == 1) ? rB.y : (r == 2) ? rB.z : rB.w;
            const int prv = (r == 0) ? prevRow : (r == 1) ? rB.x : (r == 2) ? rB.y : rB.z;
            if (cur != prv) {
                #pragma unroll
                for (int nt = 0; nt < 8; ++nt)
                    atomicAdd(outAcc + (size_t)cur * LATD + nt * 16 + c16, D[nt][r] * 64.0f);
                if (c16 < NHEAD) atomicAdd(attNorm + cur * NHEAD + c16, Dden[r]);
            }
        }
    }
}

// out[n, j] /= (attNorm[n, j/32] + 1e-8)   (mid/fallback paths)
__global__ void norm_kernel(float* __restrict__ out, const float* __restrict__ attNorm) {
    const int i = blockIdx.x * 256 + threadIdx.x;
    if (i >= NNODE * 32) return;
    const int n = i >> 5;
    const int h = (i & 31) >> 3;
    const float s = attNorm[n * NHEAD + h] + 1e-8f;
    f32x4* p = reinterpret_cast<f32x4*>(out) + i;
    f32x4 v = *p;
    v[0] /= s; v[1] /= s; v[2] /= s; v[3] /= s;
    *p = v;
}

// ================= fallback (round-1 scatter path, unsorted) =================
__global__ __launch_bounds__(512, 2) void edge_kernel(
    const int*   __restrict__ rows,
    const float* __restrict__ colEmb,
    const float* __restrict__ embeds,
    const float* __restrict__ Qw,
    const float* __restrict__ Kw,
    const float* __restrict__ Vw,
    float* __restrict__ outAcc,
    float* __restrict__ attNorm)
{
    extern __shared__ _Float16 lds[];
    _Float16* Qt = lds;
    _Float16* Kt = lds + LATD * WPAD;
    _Float16* Vt = lds + 2 * LATD * WPAD;
    const int t = threadIdx.x;
    for (int idx = t; idx < LATD * LATD; idx += 512) {
        const int d = idx >> 7, c = idx & 127;
        Qt[c * WPAD + d] = (_Float16)Qw[idx];
        Kt[c * WPAD + d] = (_Float16)Kw[idx];
        Vt[c * WPAD + d] = (_Float16)Vw[idx];
    }
    __syncthreads();
    const int lane = t & 63;
    const int c16  = lane & 15;
    const int g    = lane >> 4;
    const int wave = (blockIdx.x << 3) + (t >> 6);
    const int nw   = gridDim.x << 3;
    for (int tile = wave; tile < TILES; tile += nw) {
        const int e0 = tile << 4;
        const int eA = e0 + c16;
        const int rA = rows[eA];
        const float* xrow = embeds + (size_t)rA * LATD + g * 8;
        const float* yrow = colEmb + (size_t)eA * LATD + g * 8;
        half8 ay[4];
        f32x4 accQ[8] = {};
        f32x4 accK[8] = {};
        #pragma unroll
        for (int ks = 0; ks < 4; ++ks) {
            const int ko = ks * 32 + g * 8;
            const half8 ax = load_frag_f32(xrow + ks * 32);
            ay[ks] = load_frag_f32(yrow + ks * 32);
            #pragma unroll
            for (int nt = 0; nt < 8; ++nt) {
                const int rofs = (nt * 16 + c16) * WPAD + ko;
                const half8 bq = *reinterpret_cast<const half8*>(Qt + rofs);
                const half8 bk = *reinterpret_cast<const half8*>(Kt + rofs);
                accQ[nt] = __builtin_amdgcn_mfma_f32_16x16x32_f16(ax,     bq, accQ[nt], 0, 0, 0);
                accK[nt] = __builtin_amdgcn_mfma_f32_16x16x32_f16(ay[ks], bk, accK[nt], 0, 0, 0);
            }
        }
        f32x4 eh[4];
        #pragma unroll
        for (int h = 0; h < 4; ++h) {
            f32x4 p = accQ[2 * h] * accK[2 * h] + accQ[2 * h + 1] * accK[2 * h + 1];
            #pragma unroll
            for (int m = 1; m < 16; m <<= 1) {
                f32x4 q;
                q[0] = __shfl_xor(p[0], m);
                q[1] = __shfl_xor(p[1], m);
                q[2] = __shfl_xor(p[2], m);
                q[3] = __shfl_xor(p[3], m);
                p += q;
            }
            #pragma unroll
            for (int r = 0; r < 4; ++r)
                eh[h][r] = expf(fminf(10.0f, fmaxf(-10.0f, p[r])));
        }
        int rB[4];
        #pragma unroll
        for (int r = 0; r < 4; ++r) rB[r] = rows[e0 + g * 4 + r];
        if (c16 < NHEAD) {
            const f32x4 sel = (c16 == 0) ? eh[0] : (c16 == 1) ? eh[1] : (c16 == 2) ? eh[2] : eh[3];
            #pragma unroll
            for (int r = 0; r < 4; ++r)
                atomicAdd(attNorm + rB[r] * NHEAD + c16, sel[r]);
        }
        f32x4 accV[8] = {};
        #pragma unroll
        for (int ks = 0; ks < 4; ++ks) {
            const int ko = ks * 32 + g * 8;
            #pragma unroll
            for (int nt = 0; nt < 8; ++nt) {
                const half8 bv = *reinterpret_cast<const half8*>(Vt + (nt * 16 + c16) * WPAD + ko);
                accV[nt] = __builtin_amdgcn_mfma_f32_16x16x32_f16(ay[ks], bv, accV[nt], 0, 0, 0);
            }
        }
        #pragma unroll
        for (int nt = 0; nt < 8; ++nt) {
            const f32x4 w = accV[nt] * eh[nt >> 1];
            #pragma unroll
            for (int r = 0; r < 4; ++r)
                atomicAdd(outAcc + (size_t)rB[r] * LATD + nt * 16 + c16, w[r]);
        }
    }
}

extern "C" void kernel_launch(void* const* d_in, const int* in_sizes, int n_in,
                              void* d_out, int out_size, void* d_ws, size_t ws_size,
                              hipStream_t stream) {
    const int*   rows   = (const int*)d_in[0];
    const float* colEmb = (const float*)d_in[1];
    const float* embeds = (const float*)d_in[2];
    const float* Qw     = (const float*)d_in[3];
    const float* Kw     = (const float*)d_in[4];
    const float* Vw     = (const float*)d_in[5];
    float* out = (float*)d_out;

    // ws layout (256B-multiple chunks)
    const size_t qAllB = (size_t)NNODE * LATD * sizeof(_Float16); // 25.6 MB
    const size_t cntB  = 400128;
    const size_t offB  = 402176;                         // (NNODE+1) ints, padded
    const size_t curB  = 400128;
    const size_t eidxB = (size_t)NEDGE * sizeof(int);    // 3.2 MB
    const size_t rsrtB = (size_t)NEDGE * sizeof(int);    // 3.2 MB
    const size_t rnkB  = (size_t)NEDGE * sizeof(int);    // 3.2 MB
    const size_t partB = 512;
    const size_t wstB  = 33024;                          // (NW2+1) ints, padded
    const size_t attB  = (size_t)NNODE * NHEAD * sizeof(float);  // 1.6 MB
    const size_t smallB = qAllB + cntB + offB + curB + eidxB + rsrtB + rnkB + partB + wstB + attB;
    const size_t kvB   = (size_t)NEDGE * LATD * sizeof(_Float16); // 204.8 MB each
    const size_t fullB = smallB + 2 * kvB;

    if (ws_size >= smallB) {
        char* w = (char*)d_ws;
        _Float16* qAll    = (_Float16*)w; w += qAllB;
        int*   counts     = (int*)w;    w += cntB;
        int*   offsets    = (int*)w;    w += offB;
        int*   cursor     = (int*)w;    w += curB;
        int*   edgeIdx    = (int*)w;    w += eidxB;
        int*   rowsSorted = (int*)w;    w += rsrtB;
        int*   rank       = (int*)w;    w += rnkB;
        int*   partials   = (int*)w;    w += partB;
        int*   waveStart  = (int*)w;    w += wstB;
        float* attNorm    = (float*)w;  w += attB;
        _Float16* kS      = (_Float16*)w; w += kvB;
        _Float16* vS      = (_Float16*)w;

        hipMemsetAsync(counts, 0, (size_t)NNODE * sizeof(int), stream);
        hipMemsetAsync(out,    0, (size_t)NNODE * LATD * sizeof(float), stream); // deg-0 nodes

        const int ldsQ = LATD * WPAD * sizeof(_Float16);      // 34,816 B
        hipFuncSetAttribute((const void*)q_kernel,
                            hipFuncAttributeMaxDynamicSharedMemorySize, ldsQ);
        q_kernel<<<(QTILES + 7) / 8, 512, ldsQ, stream>>>(embeds, Qw, qAll);

        hist_kernel<<<(NEDGE + 255) / 256, 256, 0, stream>>>(rows, counts);
        scan1_kernel<<<NB, 1024, 0, stream>>>(counts, offsets, partials);
        scan2_kernel<<<NB, 1024, 0, stream>>>(offsets, cursor, partials);
        scatter_kernel<<<(NEDGE + 255) / 256, 256, 0, stream>>>(rows, cursor, edgeIdx, rowsSorted, rank);

        const int ldsN = 2 * LATD * WPAD * sizeof(_Float16);  // 69,632 B

        if (ws_size >= fullB) {
            // ---- full path: kv transform + scalar accumulate ----
            partition_kernel<<<(NW2 + 256) / 256, 256, 0, stream>>>(offsets, waveStart);

            hipFuncSetAttribute((const void*)kv_kernel,
                                hipFuncAttributeMaxDynamicSharedMemorySize, ldsN);
            kv_kernel<<<512, 512, ldsN, stream>>>(rank, colEmb, Kw, Vw, kS, vS);

            accum_kernel<<<NW2 / 4, 256, 0, stream>>>(waveStart, rowsSorted, kS, vS, qAll, out);
        } else {
            // ---- mid tier: R7 sorted-edge P-MFMA path ----
            hipMemsetAsync(attNorm, 0, (size_t)NNODE * NHEAD * sizeof(float), stream);
            hipFuncSetAttribute((const void*)sorted_edge_kernel,
                                hipFuncAttributeMaxDynamicSharedMemorySize, ldsN);
            const int nWaves = 512 * 8;
            const int tpw = (TILES + nWaves - 1) / nWaves;      // 13
            sorted_edge_kernel<<<512, 512, ldsN, stream>>>(
                edgeIdx, rowsSorted, colEmb, qAll, Kw, Vw, out, attNorm, tpw);
            const int nVec = NNODE * 32;
            norm_kernel<<<(nVec + 255) / 256, 256, 0, stream>>>(out, attNorm);
        }
    } else {
        // fallback: round-1 scatter path
        float* attNorm = (float*)d_ws;
        const int ldsBytes = 3 * LATD * WPAD * sizeof(_Float16);  // 104448 B
        hipMemsetAsync(out,     0, (size_t)NNODE * LATD  * sizeof(float), stream);
        hipMemsetAsync(attNorm, 0, (size_t)NNODE * NHEAD * sizeof(float), stream);
        hipFuncSetAttribute((const void*)edge_kernel,
                            hipFuncAttributeMaxDynamicSharedMemorySize, ldsBytes);
        edge_kernel<<<512, 512, ldsBytes, stream>>>(rows, colEmb, embeds, Qw, Kw, Vw, out, attNorm);
        const int nVec = NNODE * 32;
        norm_kernel<<<(nVec + 255) / 256, 256, 0, stream>>>(out, attNorm);
    }
}